// Round 1
// baseline (327.136 us; speedup 1.0000x reference)
//
#include <hip/hip_runtime.h>
#include <stdint.h>

#define M_TOTAL 16384
#define N_TOTAL 572
#define K_TOTAL 1024
#define D_TOTAL 1024

// ---------------------------------------------------------------------------
// Kernel 1: pre = core @ W1 + b1   (f32 vector GEMM, 64x64 tile, 4x4/thread)
// ---------------------------------------------------------------------------
__global__ __launch_bounds__(256) void gemm_pre(const float* __restrict__ A,
                                                const float* __restrict__ W,
                                                const float* __restrict__ b1,
                                                float* __restrict__ C) {
  __shared__ float As[16][64];   // As[k][m]
  __shared__ float Bs[16][64];   // Bs[k][n]
  const int t = threadIdx.x;
  const int tx = t & 15, ty = t >> 4;
  const int m0 = blockIdx.y * 64;
  const int n0 = blockIdx.x * 64;
  const int ar = t >> 2, ac4 = (t & 3) << 2;   // A loader: row, k-offset
  const int bk = t >> 4, bn4 = (t & 15) << 2;  // B loader: k, n-offset
  float acc[4][4] = {};

  for (int k0 = 0; k0 < K_TOTAL; k0 += 16) {
    float4 av = *reinterpret_cast<const float4*>(A + (size_t)(m0 + ar) * K_TOTAL + k0 + ac4);
    As[ac4 + 0][ar] = av.x;
    As[ac4 + 1][ar] = av.y;
    As[ac4 + 2][ar] = av.z;
    As[ac4 + 3][ar] = av.w;
    float4 bv = make_float4(0.f, 0.f, 0.f, 0.f);
    const int gn = n0 + bn4;
    if (gn < N_TOTAL)  // 572 % 4 == 0, so a valid float4 never straddles the edge
      bv = *reinterpret_cast<const float4*>(W + (size_t)(k0 + bk) * N_TOTAL + gn);
    *reinterpret_cast<float4*>(&Bs[bk][bn4]) = bv;
    __syncthreads();
#pragma unroll
    for (int kk = 0; kk < 16; ++kk) {
      float4 a = *reinterpret_cast<const float4*>(&As[kk][ty << 2]);
      float4 b = *reinterpret_cast<const float4*>(&Bs[kk][tx << 2]);
      const float aa[4] = {a.x, a.y, a.z, a.w};
      const float bb[4] = {b.x, b.y, b.z, b.w};
#pragma unroll
      for (int i = 0; i < 4; ++i)
#pragma unroll
        for (int j = 0; j < 4; ++j)
          acc[i][j] = fmaf(aa[i], bb[j], acc[i][j]);
    }
    __syncthreads();
  }

#pragma unroll
  for (int j = 0; j < 4; ++j) {
    const int n = n0 + (tx << 2) + j;
    if (n < N_TOTAL) {
      const float bj = b1[n];
#pragma unroll
      for (int i = 0; i < 4; ++i) {
        const int m = m0 + (ty << 2) + i;
        C[(size_t)m * N_TOTAL + n] = acc[i][j] + bj;
      }
    }
  }
}

// ---------------------------------------------------------------------------
// JAX threefry2x32, key(42) -> (0,42); partitionable random_bits (32-bit):
// bits[i] = x0 ^ x1 of Threefry2x32((0,42), (hi=0, lo=i))
// ---------------------------------------------------------------------------
__device__ __forceinline__ float jax_gumbel(uint32_t idx) {
  const uint32_t ks0 = 0u;
  const uint32_t ks1 = 42u;
  const uint32_t ks2 = 0x1BD11BDAu ^ ks0 ^ ks1;
  uint32_t x0 = ks0;        // counts_hi (0) + ks0
  uint32_t x1 = idx + ks1;  // counts_lo (i) + ks1
#define TF_ROUND(r) { x0 += x1; x1 = (x1 << (r)) | (x1 >> (32 - (r))); x1 ^= x0; }
  TF_ROUND(13) TF_ROUND(15) TF_ROUND(26) TF_ROUND(6)
  x0 += ks1; x1 += ks2 + 1u;
  TF_ROUND(17) TF_ROUND(29) TF_ROUND(16) TF_ROUND(24)
  x0 += ks2; x1 += ks0 + 2u;
  TF_ROUND(13) TF_ROUND(15) TF_ROUND(26) TF_ROUND(6)
  x0 += ks0; x1 += ks1 + 3u;
  TF_ROUND(17) TF_ROUND(29) TF_ROUND(16) TF_ROUND(24)
  x0 += ks1; x1 += ks2 + 4u;
  TF_ROUND(13) TF_ROUND(15) TF_ROUND(26) TF_ROUND(6)
  x0 += ks2; x1 += ks0 + 5u;
#undef TF_ROUND
  const uint32_t bits = x0 ^ x1;
  // uniform in [tiny, 1): float in [1,2) from mantissa bits, minus 1
  union { uint32_t u; float f; } cvt;
  cvt.u = (bits >> 9) | 0x3F800000u;
  const float fl = cvt.f - 1.0f;
  const float TINY = 1.1754943508222875e-38f;       // finfo(f32).tiny
  const float u = fmaxf(TINY, fl * 1.0f + TINY);    // (maxval-minval) rounds to 1.0f
  return -logf(-logf(u));
}

// ---------------------------------------------------------------------------
// Kernel 2: per row -- softmax (in-place probs), gumbel argmax, gather+relu+add
// ---------------------------------------------------------------------------
__global__ __launch_bounds__(256) void head_kernel(
    float* __restrict__ pre_probs,   // [M, 572]: reads pre, writes probs
    const float* __restrict__ core,  // [M, 1024]
    const float* __restrict__ W2,    // [572, 1024]
    const float* __restrict__ b2,    // [1024]
    float* __restrict__ out1)        // [M, 1024]
{
  const int row = blockIdx.x;
  const int t = threadIdx.x;
  const int lane = t & 63, wid = t >> 6;

  __shared__ float s_max[4];
  __shared__ float s_sum[4];
  __shared__ float s_av[4];
  __shared__ int   s_ai[4];

  float* xrow = pre_probs + (size_t)row * N_TOTAL;
  const int c0 = t, c1 = t + 256, c2 = t + 512;
  const bool v1 = (c1 < N_TOTAL), v2 = (c2 < N_TOTAL);
  const float NEG_INF = -__builtin_inff();

  const float x0v = xrow[c0];
  const float x1v = v1 ? xrow[c1] : NEG_INF;
  const float x2v = v2 ? xrow[c2] : NEG_INF;

  // ---- row max ----
  float vmax = fmaxf(x0v, fmaxf(x1v, x2v));
#pragma unroll
  for (int off = 32; off > 0; off >>= 1)
    vmax = fmaxf(vmax, __shfl_xor(vmax, off, 64));
  if (lane == 0) s_max[wid] = vmax;
  __syncthreads();
  const float m = fmaxf(fmaxf(s_max[0], s_max[1]), fmaxf(s_max[2], s_max[3]));

  // ---- sum of exp ----
  const float e0 = expf(x0v - m);
  const float e1 = v1 ? expf(x1v - m) : 0.0f;
  const float e2 = v2 ? expf(x2v - m) : 0.0f;
  float vsum = e0 + e1 + e2;
#pragma unroll
  for (int off = 32; off > 0; off >>= 1)
    vsum += __shfl_xor(vsum, off, 64);
  if (lane == 0) s_sum[wid] = vsum;
  __syncthreads();
  const float sum = (s_sum[0] + s_sum[1]) + (s_sum[2] + s_sum[3]);

  // ---- probs (overwrite pre in place; all reads of this row already done) ----
  const float lse = logf(sum);
  xrow[c0] = e0 / sum;
  if (v1) xrow[c1] = e1 / sum;
  if (v2) xrow[c2] = e2 / sum;

  // ---- gumbel + log_softmax, argmax (first-index tie-break) ----
  const uint32_t base = (uint32_t)row * (uint32_t)N_TOTAL;
  float bv = jax_gumbel(base + c0) + ((x0v - m) - lse);
  int bi = c0;
  if (v1) {
    const float s1 = jax_gumbel(base + c1) + ((x1v - m) - lse);
    if (s1 > bv) { bv = s1; bi = c1; }
  }
  if (v2) {
    const float s2 = jax_gumbel(base + c2) + ((x2v - m) - lse);
    if (s2 > bv) { bv = s2; bi = c2; }
  }
#pragma unroll
  for (int off = 32; off > 0; off >>= 1) {
    const float ov = __shfl_xor(bv, off, 64);
    const int oi = __shfl_xor(bi, off, 64);
    if (ov > bv || (ov == bv && oi < bi)) { bv = ov; bi = oi; }
  }
  if (lane == 0) { s_av[wid] = bv; s_ai[wid] = bi; }
  __syncthreads();
  float best = s_av[0]; int action = s_ai[0];
#pragma unroll
  for (int w = 1; w < 4; ++w) {
    if (s_av[w] > best || (s_av[w] == best && s_ai[w] < action)) {
      best = s_av[w]; action = s_ai[w];
    }
  }

  // ---- out1 = relu(W2[action] + b2) + core ----
  const float* __restrict__ w2row = W2 + (size_t)action * D_TOTAL;
  const float* __restrict__ crow = core + (size_t)row * D_TOTAL;
  float* __restrict__ orow = out1 + (size_t)row * D_TOTAL;
#pragma unroll
  for (int d = t; d < D_TOTAL; d += 256) {
    const float h = w2row[d] + b2[d];
    orow[d] = fmaxf(h, 0.0f) + crow[d];
  }
}

// ---------------------------------------------------------------------------
extern "C" void kernel_launch(void* const* d_in, const int* in_sizes, int n_in,
                              void* d_out, int out_size, void* d_ws, size_t ws_size,
                              hipStream_t stream) {
  const float* core = (const float*)d_in[0];  // [16384,1024]
  const float* W1   = (const float*)d_in[1];  // [1024,572]
  const float* b1   = (const float*)d_in[2];  // [572]
  const float* W2   = (const float*)d_in[3];  // [572,1024]
  const float* b2   = (const float*)d_in[4];  // [1024]

  float* probs = (float*)d_out;                                  // [16384,572]
  float* out1  = (float*)d_out + (size_t)M_TOTAL * N_TOTAL;      // [16384,1024]

  // pre -> probs region (overwritten in-place by head_kernel)
  dim3 g1((N_TOTAL + 63) / 64, M_TOTAL / 64);
  gemm_pre<<<g1, 256, 0, stream>>>(core, W1, b1, probs);

  head_kernel<<<M_TOTAL, 256, 0, stream>>>(probs, core, W2, b2, out1);
}

// Round 2
// 167.924 us; speedup vs baseline: 1.9481x; 1.9481x over previous
//
#include <hip/hip_runtime.h>
#include <hip/hip_fp16.h>
#include <stdint.h>

#define M_TOTAL 16384
#define N_TOTAL 572
#define N_PAD   640
#define K_TOTAL 1024
#define D_TOTAL 1024

typedef _Float16 f16;
typedef __attribute__((ext_vector_type(8))) _Float16 f16x8;
typedef __attribute__((ext_vector_type(4))) float f32x4;

// ---------------------------------------------------------------------------
// convert_a: core f32 [M,K] -> hi/lo f16 planes (stored in out1 region)
// ---------------------------------------------------------------------------
__global__ __launch_bounds__(256) void convert_a(const float* __restrict__ A,
                                                 f16* __restrict__ hi,
                                                 f16* __restrict__ lo) {
  const size_t i = ((size_t)blockIdx.x * 256 + threadIdx.x) * 8;
  float4 v0 = *reinterpret_cast<const float4*>(A + i);
  float4 v1 = *reinterpret_cast<const float4*>(A + i + 4);
  const float x[8] = {v0.x, v0.y, v0.z, v0.w, v1.x, v1.y, v1.z, v1.w};
  f16x8 vh, vl;
#pragma unroll
  for (int j = 0; j < 8; ++j) {
    f16 h = (f16)x[j];
    vh[j] = h;
    vl[j] = (f16)(x[j] - (float)h);
  }
  *reinterpret_cast<f16x8*>(hi + i) = vh;
  *reinterpret_cast<f16x8*>(lo + i) = vl;
}

// ---------------------------------------------------------------------------
// convert_w: W1 f32 [K,572] -> transposed hi/lo f16 planes [640,K] (d_ws),
// rows 572..639 zero-filled so the GEMM needs no B masks.
// ---------------------------------------------------------------------------
__global__ __launch_bounds__(256) void convert_w(const float* __restrict__ W,
                                                 f16* __restrict__ thi,
                                                 f16* __restrict__ tlo) {
  __shared__ float tile[32][33];
  const int n0 = blockIdx.x * 32, k0 = blockIdx.y * 32;
  const int tx = threadIdx.x & 31, ty = threadIdx.x >> 5;  // 32 x 8
#pragma unroll
  for (int s = 0; s < 32; s += 8) {
    const int k = k0 + ty + s, n = n0 + tx;
    tile[ty + s][tx] = (n < N_TOTAL) ? W[(size_t)k * N_TOTAL + n] : 0.0f;
  }
  __syncthreads();
#pragma unroll
  for (int s = 0; s < 32; s += 8) {
    const int n = n0 + ty + s, k = k0 + tx;
    const float x = tile[tx][ty + s];
    const f16 h = (f16)x;
    thi[(size_t)n * K_TOTAL + k] = h;
    tlo[(size_t)n * K_TOTAL + k] = (f16)(x - (float)h);
  }
}

// ---------------------------------------------------------------------------
// gemm_split: pre = core @ W1 + b1 via 3-pass split-f16 MFMA.
// Block 256 thr = 4 waves (2x2), tile 128x128, BK=32, wave tile 64x64.
// ---------------------------------------------------------------------------
#define BM 128
#define BN 128
#define BK 32
#define LDK 40  // padded LDS row length in f16 (80B -> 2-way bank alias, free)

__global__ __launch_bounds__(256) void gemm_split(
    const f16* __restrict__ aHi, const f16* __restrict__ aLo,
    const f16* __restrict__ bHi, const f16* __restrict__ bLo,
    const float* __restrict__ b1, float* __restrict__ C) {
  __shared__ __align__(16) f16 As[2][BM][LDK];
  __shared__ __align__(16) f16 Bs[2][BN][LDK];

  const int t = threadIdx.x;
  const int lane = t & 63, wid = t >> 6;
  const int wm = wid >> 1, wn = wid & 1;
  const int m0 = blockIdx.y * BM, n0 = blockIdx.x * BN;

  // staging: unit u = it*256 + t; row = u>>2 (0..127), 16B segment = u&3
  const int r0 = t >> 2, sg = t & 3;

  f32x4 acc[4][4] = {};
  f16x8 pa[2][2], pb[2][2];  // [plane][iter] global->reg prefetch

  auto LOADK = [&](int k0) {
#pragma unroll
    for (int it = 0; it < 2; ++it) {
      const size_t ra = (size_t)(m0 + r0 + it * 64) * K_TOTAL + k0 + sg * 8;
      const size_t rb = (size_t)(n0 + r0 + it * 64) * K_TOTAL + k0 + sg * 8;
      pa[0][it] = *reinterpret_cast<const f16x8*>(aHi + ra);
      pa[1][it] = *reinterpret_cast<const f16x8*>(aLo + ra);
      pb[0][it] = *reinterpret_cast<const f16x8*>(bHi + rb);
      pb[1][it] = *reinterpret_cast<const f16x8*>(bLo + rb);
    }
  };
  auto WRITELDS = [&]() {
#pragma unroll
    for (int p = 0; p < 2; ++p)
#pragma unroll
      for (int it = 0; it < 2; ++it) {
        *reinterpret_cast<f16x8*>(&As[p][r0 + it * 64][sg * 8]) = pa[p][it];
        *reinterpret_cast<f16x8*>(&Bs[p][r0 + it * 64][sg * 8]) = pb[p][it];
      }
  };

  const int fr = lane & 15, fq = lane >> 4;

  LOADK(0);
  for (int k0 = 0; k0 < K_TOTAL; k0 += BK) {
    __syncthreads();  // previous compute done; LDS reusable
    WRITELDS();
    if (k0 + BK < K_TOTAL) LOADK(k0 + BK);  // in flight across the compute
    __syncthreads();

    f16x8 ah[4], al[4];
#pragma unroll
    for (int mi = 0; mi < 4; ++mi) {
      ah[mi] = *reinterpret_cast<const f16x8*>(&As[0][wm * 64 + mi * 16 + fr][fq * 8]);
      al[mi] = *reinterpret_cast<const f16x8*>(&As[1][wm * 64 + mi * 16 + fr][fq * 8]);
    }
#pragma unroll
    for (int ni = 0; ni < 4; ++ni) {
      const f16x8 bh = *reinterpret_cast<const f16x8*>(&Bs[0][wn * 64 + ni * 16 + fr][fq * 8]);
      const f16x8 bl = *reinterpret_cast<const f16x8*>(&Bs[1][wn * 64 + ni * 16 + fr][fq * 8]);
#pragma unroll
      for (int mi = 0; mi < 4; ++mi) {
        acc[mi][ni] = __builtin_amdgcn_mfma_f32_16x16x32_f16(ah[mi], bh, acc[mi][ni], 0, 0, 0);
        acc[mi][ni] = __builtin_amdgcn_mfma_f32_16x16x32_f16(ah[mi], bl, acc[mi][ni], 0, 0, 0);
        acc[mi][ni] = __builtin_amdgcn_mfma_f32_16x16x32_f16(al[mi], bh, acc[mi][ni], 0, 0, 0);
      }
    }
  }

  // epilogue: + b1, masked store (C/D layout: col=lane&15, row=(lane>>4)*4+r)
#pragma unroll
  for (int ni = 0; ni < 4; ++ni) {
    const int n = n0 + wn * 64 + ni * 16 + fr;
    if (n >= N_TOTAL) continue;
    const float bb = b1[n];
#pragma unroll
    for (int mi = 0; mi < 4; ++mi) {
      const int mbase = m0 + wm * 64 + mi * 16 + fq * 4;
#pragma unroll
      for (int r = 0; r < 4; ++r)
        C[(size_t)(mbase + r) * N_TOTAL + n] = acc[mi][ni][r] + bb;
    }
  }
}

// ---------------------------------------------------------------------------
// Fallback f32 vector GEMM (only if ws_size is too small for W1 planes)
// ---------------------------------------------------------------------------
__global__ __launch_bounds__(256) void gemm_pre(const float* __restrict__ A,
                                                const float* __restrict__ W,
                                                const float* __restrict__ b1,
                                                float* __restrict__ C) {
  __shared__ float As[16][64];
  __shared__ float Bs[16][64];
  const int t = threadIdx.x;
  const int tx = t & 15, ty = t >> 4;
  const int m0 = blockIdx.y * 64;
  const int n0 = blockIdx.x * 64;
  const int ar = t >> 2, ac4 = (t & 3) << 2;
  const int bk = t >> 4, bn4 = (t & 15) << 2;
  float acc[4][4] = {};
  for (int k0 = 0; k0 < K_TOTAL; k0 += 16) {
    float4 av = *reinterpret_cast<const float4*>(A + (size_t)(m0 + ar) * K_TOTAL + k0 + ac4);
    As[ac4 + 0][ar] = av.x;
    As[ac4 + 1][ar] = av.y;
    As[ac4 + 2][ar] = av.z;
    As[ac4 + 3][ar] = av.w;
    float4 bv = make_float4(0.f, 0.f, 0.f, 0.f);
    const int gn = n0 + bn4;
    if (gn < N_TOTAL)
      bv = *reinterpret_cast<const float4*>(W + (size_t)(k0 + bk) * N_TOTAL + gn);
    *reinterpret_cast<float4*>(&Bs[bk][bn4]) = bv;
    __syncthreads();
#pragma unroll
    for (int kk = 0; kk < 16; ++kk) {
      float4 a = *reinterpret_cast<const float4*>(&As[kk][ty << 2]);
      float4 b = *reinterpret_cast<const float4*>(&Bs[kk][tx << 2]);
      const float aa[4] = {a.x, a.y, a.z, a.w};
      const float bb[4] = {b.x, b.y, b.z, b.w};
#pragma unroll
      for (int i = 0; i < 4; ++i)
#pragma unroll
        for (int j = 0; j < 4; ++j)
          acc[i][j] = fmaf(aa[i], bb[j], acc[i][j]);
    }
    __syncthreads();
  }
#pragma unroll
  for (int j = 0; j < 4; ++j) {
    const int n = n0 + (tx << 2) + j;
    if (n < N_TOTAL) {
      const float bj = b1[n];
#pragma unroll
      for (int i = 0; i < 4; ++i) {
        const int m = m0 + (ty << 2) + i;
        C[(size_t)m * N_TOTAL + n] = acc[i][j] + bj;
      }
    }
  }
}

// ---------------------------------------------------------------------------
// JAX threefry2x32, key(42) -> (0,42); partitionable random_bits (32-bit)
// ---------------------------------------------------------------------------
__device__ __forceinline__ float jax_gumbel(uint32_t idx) {
  const uint32_t ks0 = 0u;
  const uint32_t ks1 = 42u;
  const uint32_t ks2 = 0x1BD11BDAu ^ ks0 ^ ks1;
  uint32_t x0 = ks0;
  uint32_t x1 = idx + ks1;
#define TF_ROUND(r) { x0 += x1; x1 = (x1 << (r)) | (x1 >> (32 - (r))); x1 ^= x0; }
  TF_ROUND(13) TF_ROUND(15) TF_ROUND(26) TF_ROUND(6)
  x0 += ks1; x1 += ks2 + 1u;
  TF_ROUND(17) TF_ROUND(29) TF_ROUND(16) TF_ROUND(24)
  x0 += ks2; x1 += ks0 + 2u;
  TF_ROUND(13) TF_ROUND(15) TF_ROUND(26) TF_ROUND(6)
  x0 += ks0; x1 += ks1 + 3u;
  TF_ROUND(17) TF_ROUND(29) TF_ROUND(16) TF_ROUND(24)
  x0 += ks1; x1 += ks2 + 4u;
  TF_ROUND(13) TF_ROUND(15) TF_ROUND(26) TF_ROUND(6)
  x0 += ks2; x1 += ks0 + 5u;
#undef TF_ROUND
  const uint32_t bits = x0 ^ x1;
  union { uint32_t u; float f; } cvt;
  cvt.u = (bits >> 9) | 0x3F800000u;
  const float fl = cvt.f - 1.0f;
  const float TINY = 1.1754943508222875e-38f;
  const float u = fmaxf(TINY, fl * 1.0f + TINY);
  return -logf(-logf(u));
}

// ---------------------------------------------------------------------------
// head_kernel: per row -- softmax (in-place), gumbel argmax, gather+relu+add
// ---------------------------------------------------------------------------
__global__ __launch_bounds__(256) void head_kernel(
    float* __restrict__ pre_probs,
    const float* __restrict__ core,
    const float* __restrict__ W2,
    const float* __restrict__ b2,
    float* __restrict__ out1) {
  const int row = blockIdx.x;
  const int t = threadIdx.x;
  const int lane = t & 63, wid = t >> 6;

  __shared__ float s_max[4];
  __shared__ float s_sum[4];
  __shared__ float s_av[4];
  __shared__ int   s_ai[4];

  float* xrow = pre_probs + (size_t)row * N_TOTAL;
  const int c0 = t, c1 = t + 256, c2 = t + 512;
  const bool v1 = (c1 < N_TOTAL), v2 = (c2 < N_TOTAL);
  const float NEG_INF = -__builtin_inff();

  const float x0v = xrow[c0];
  const float x1v = v1 ? xrow[c1] : NEG_INF;
  const float x2v = v2 ? xrow[c2] : NEG_INF;

  float vmax = fmaxf(x0v, fmaxf(x1v, x2v));
#pragma unroll
  for (int off = 32; off > 0; off >>= 1)
    vmax = fmaxf(vmax, __shfl_xor(vmax, off, 64));
  if (lane == 0) s_max[wid] = vmax;
  __syncthreads();
  const float m = fmaxf(fmaxf(s_max[0], s_max[1]), fmaxf(s_max[2], s_max[3]));

  const float e0 = expf(x0v - m);
  const float e1 = v1 ? expf(x1v - m) : 0.0f;
  const float e2 = v2 ? expf(x2v - m) : 0.0f;
  float vsum = e0 + e1 + e2;
#pragma unroll
  for (int off = 32; off > 0; off >>= 1)
    vsum += __shfl_xor(vsum, off, 64);
  if (lane == 0) s_sum[wid] = vsum;
  __syncthreads();
  const float sum = (s_sum[0] + s_sum[1]) + (s_sum[2] + s_sum[3]);

  const float lse = logf(sum);
  xrow[c0] = e0 / sum;
  if (v1) xrow[c1] = e1 / sum;
  if (v2) xrow[c2] = e2 / sum;

  const uint32_t base = (uint32_t)row * (uint32_t)N_TOTAL;
  float bv = jax_gumbel(base + c0) + ((x0v - m) - lse);
  int bi = c0;
  if (v1) {
    const float s1 = jax_gumbel(base + c1) + ((x1v - m) - lse);
    if (s1 > bv) { bv = s1; bi = c1; }
  }
  if (v2) {
    const float s2 = jax_gumbel(base + c2) + ((x2v - m) - lse);
    if (s2 > bv) { bv = s2; bi = c2; }
  }
#pragma unroll
  for (int off = 32; off > 0; off >>= 1) {
    const float ov = __shfl_xor(bv, off, 64);
    const int oi = __shfl_xor(bi, off, 64);
    if (ov > bv || (ov == bv && oi < bi)) { bv = ov; bi = oi; }
  }
  if (lane == 0) { s_av[wid] = bv; s_ai[wid] = bi; }
  __syncthreads();
  float best = s_av[0]; int action = s_ai[0];
#pragma unroll
  for (int w = 1; w < 4; ++w) {
    if (s_av[w] > best || (s_av[w] == best && s_ai[w] < action)) {
      best = s_av[w]; action = s_ai[w];
    }
  }

  const float* __restrict__ w2row = W2 + (size_t)action * D_TOTAL;
  const float* __restrict__ crow = core + (size_t)row * D_TOTAL;
  float* __restrict__ orow = out1 + (size_t)row * D_TOTAL;
#pragma unroll
  for (int d = t; d < D_TOTAL; d += 256) {
    const float h = w2row[d] + b2[d];
    orow[d] = fmaxf(h, 0.0f) + crow[d];
  }
}

// ---------------------------------------------------------------------------
extern "C" void kernel_launch(void* const* d_in, const int* in_sizes, int n_in,
                              void* d_out, int out_size, void* d_ws, size_t ws_size,
                              hipStream_t stream) {
  const float* core = (const float*)d_in[0];  // [16384,1024]
  const float* W1   = (const float*)d_in[1];  // [1024,572]
  const float* b1   = (const float*)d_in[2];  // [572]
  const float* W2   = (const float*)d_in[3];  // [572,1024]
  const float* b2   = (const float*)d_in[4];  // [1024]

  float* probs = (float*)d_out;                              // [16384,572]
  float* out1  = (float*)d_out + (size_t)M_TOTAL * N_TOTAL;  // [16384,1024]

  const size_t wneed = (size_t)2 * N_PAD * K_TOTAL * sizeof(f16);  // 2.6 MB
  if (ws_size >= wneed) {
    f16* aHi = (f16*)out1;  // out1 region = exactly 2 x 32MB planes
    f16* aLo = aHi + (size_t)M_TOTAL * K_TOTAL;
    f16* wHi = (f16*)d_ws;
    f16* wLo = wHi + (size_t)N_PAD * K_TOTAL;

    convert_a<<<(M_TOTAL * K_TOTAL) / (256 * 8), 256, 0, stream>>>(core, aHi, aLo);
    convert_w<<<dim3(N_PAD / 32, K_TOTAL / 32), 256, 0, stream>>>(W1, wHi, wLo);
    gemm_split<<<dim3(N_PAD / BN, M_TOTAL / BM), 256, 0, stream>>>(aHi, aLo, wHi, wLo, b1, probs);
  } else {
    gemm_pre<<<dim3((N_TOTAL + 63) / 64, M_TOTAL / 64), 256, 0, stream>>>(core, W1, b1, probs);
  }

  head_kernel<<<M_TOTAL, 256, 0, stream>>>(probs, core, W2, b2, out1);
}

// Round 3
// 122.806 us; speedup vs baseline: 2.6638x; 1.3674x over previous
//
#include <hip/hip_runtime.h>
#include <hip/hip_fp16.h>
#include <stdint.h>

#define M_TOTAL 16384
#define N_TOTAL 572
#define N_PAD   640
#define K_TOTAL 1024
#define D_TOTAL 1024

typedef _Float16 f16;
typedef __attribute__((ext_vector_type(8))) _Float16 f16x8;
typedef __attribute__((ext_vector_type(4))) float f32x4;

// ---------------------------------------------------------------------------
// convert_w: W1 f32 [K,572] -> transposed hi/lo f16 planes [640,K] (d_ws),
// rows 572..639 zero-filled so the GEMM needs no B masks.
// ---------------------------------------------------------------------------
__global__ __launch_bounds__(256) void convert_w(const float* __restrict__ W,
                                                 f16* __restrict__ thi,
                                                 f16* __restrict__ tlo) {
  __shared__ float tile[32][33];
  const int n0 = blockIdx.x * 32, k0 = blockIdx.y * 32;
  const int tx = threadIdx.x & 31, ty = threadIdx.x >> 5;  // 32 x 8
#pragma unroll
  for (int s = 0; s < 32; s += 8) {
    const int k = k0 + ty + s, n = n0 + tx;
    tile[ty + s][tx] = (n < N_TOTAL) ? W[(size_t)k * N_TOTAL + n] : 0.0f;
  }
  __syncthreads();
#pragma unroll
  for (int s = 0; s < 32; s += 8) {
    const int n = n0 + ty + s, k = k0 + tx;
    const float x = tile[tx][ty + s];
    const f16 h = (f16)x;
    thi[(size_t)n * K_TOTAL + k] = h;
    tlo[(size_t)n * K_TOTAL + k] = (f16)(x - (float)h);
  }
}

// ---------------------------------------------------------------------------
// gemm_fused: pre = core @ W1 + b1 via 3-pass split-f16 MFMA.
// A converted f32 -> hi/lo f16 in-kernel (no separate convert pass).
// 256 thr = 8 waves (4x2), tile 128x128, BK=32, wave tile 32x64.
// Grid 640 blocks, XCD-swizzled: each XCD owns 16 m-panels x all 5 n-blocks.
// ---------------------------------------------------------------------------
#define BM 128
#define BN 128
#define BK 32
#define LDK 40  // padded LDS row (80B): 2-way bank alias only (free, m136)

__global__ __launch_bounds__(256) void gemm_fused(
    const float* __restrict__ A,
    const f16* __restrict__ bHi, const f16* __restrict__ bLo,
    const float* __restrict__ b1, float* __restrict__ C) {
  __shared__ __align__(16) f16 As[2][BM][LDK];
  __shared__ __align__(16) f16 Bs[2][BN][LDK];

  const int t = threadIdx.x;
  const int lane = t & 63, wid = t >> 6;
  const int wm = wid >> 1, wn = wid & 1;  // 4x2 wave grid, wave tile 32x64

  // bijective XCD swizzle: 640 = 8 XCDs x 80 blocks
  const int bid = blockIdx.x;
  const int wg = (bid & 7) * 80 + (bid >> 3);
  const int nb = wg % 5, mb = wg / 5;
  const int m0 = mb * BM, n0 = nb * BN;

  // staging: thread t covers row r0 = t>>1, 16-element half hf = t&1
  const int r0 = t >> 1, hf = t & 1;

  f32x4 acc[2][4] = {};
  float4 pa[4];        // 16 f32 of A (converted to hi/lo at LDS-write time)
  f16x8 pbh[2], pbl[2];

  const float* aBase = A + (size_t)(m0 + r0) * K_TOTAL + hf * 16;
  const f16* bhBase = bHi + (size_t)(n0 + r0) * K_TOTAL + hf * 16;
  const f16* blBase = bLo + (size_t)(n0 + r0) * K_TOTAL + hf * 16;

  auto LOADK = [&](int k0) {
#pragma unroll
    for (int i = 0; i < 4; ++i)
      pa[i] = *reinterpret_cast<const float4*>(aBase + k0 + i * 4);
#pragma unroll
    for (int i = 0; i < 2; ++i) {
      pbh[i] = *reinterpret_cast<const f16x8*>(bhBase + k0 + i * 8);
      pbl[i] = *reinterpret_cast<const f16x8*>(blBase + k0 + i * 8);
    }
  };
  auto WRITELDS = [&]() {
    const float x[16] = {pa[0].x, pa[0].y, pa[0].z, pa[0].w,
                         pa[1].x, pa[1].y, pa[1].z, pa[1].w,
                         pa[2].x, pa[2].y, pa[2].z, pa[2].w,
                         pa[3].x, pa[3].y, pa[3].z, pa[3].w};
    f16x8 vh[2], vl[2];
#pragma unroll
    for (int e = 0; e < 16; ++e) {
      const f16 h = (f16)x[e];
      vh[e >> 3][e & 7] = h;
      vl[e >> 3][e & 7] = (f16)(x[e] - (float)h);
    }
#pragma unroll
    for (int i = 0; i < 2; ++i) {
      *reinterpret_cast<f16x8*>(&As[0][r0][hf * 16 + i * 8]) = vh[i];
      *reinterpret_cast<f16x8*>(&As[1][r0][hf * 16 + i * 8]) = vl[i];
      *reinterpret_cast<f16x8*>(&Bs[0][r0][hf * 16 + i * 8]) = pbh[i];
      *reinterpret_cast<f16x8*>(&Bs[1][r0][hf * 16 + i * 8]) = pbl[i];
    }
  };

  const int fr = lane & 15, fq = lane >> 4;

  LOADK(0);
  for (int k0 = 0; k0 < K_TOTAL; k0 += BK) {
    __syncthreads();  // previous compute done; LDS reusable
    WRITELDS();
    if (k0 + BK < K_TOTAL) LOADK(k0 + BK);  // next tile in flight over compute
    __syncthreads();

    f16x8 ah[2], al[2];
#pragma unroll
    for (int mi = 0; mi < 2; ++mi) {
      const int row = wm * 32 + mi * 16 + fr;
      ah[mi] = *reinterpret_cast<const f16x8*>(&As[0][row][fq * 8]);
      al[mi] = *reinterpret_cast<const f16x8*>(&As[1][row][fq * 8]);
    }
#pragma unroll
    for (int ni = 0; ni < 4; ++ni) {
      const int row = wn * 64 + ni * 16 + fr;
      const f16x8 bh = *reinterpret_cast<const f16x8*>(&Bs[0][row][fq * 8]);
      const f16x8 bl = *reinterpret_cast<const f16x8*>(&Bs[1][row][fq * 8]);
#pragma unroll
      for (int mi = 0; mi < 2; ++mi) {
        acc[mi][ni] = __builtin_amdgcn_mfma_f32_16x16x32_f16(ah[mi], bh, acc[mi][ni], 0, 0, 0);
        acc[mi][ni] = __builtin_amdgcn_mfma_f32_16x16x32_f16(ah[mi], bl, acc[mi][ni], 0, 0, 0);
        acc[mi][ni] = __builtin_amdgcn_mfma_f32_16x16x32_f16(al[mi], bh, acc[mi][ni], 0, 0, 0);
      }
    }
  }

  // epilogue: + b1, masked store (C/D layout: col=lane&15, row=(lane>>4)*4+r)
#pragma unroll
  for (int ni = 0; ni < 4; ++ni) {
    const int n = n0 + wn * 64 + ni * 16 + fr;
    if (n >= N_TOTAL) continue;
    const float bb = b1[n];
#pragma unroll
    for (int mi = 0; mi < 2; ++mi) {
      const int mbase = m0 + wm * 32 + mi * 16 + fq * 4;
#pragma unroll
      for (int r = 0; r < 4; ++r)
        C[(size_t)(mbase + r) * N_TOTAL + n] = acc[mi][ni][r] + bb;
    }
  }
}

// ---------------------------------------------------------------------------
// Fallback f32 vector GEMM (only if ws_size is too small for W1 planes)
// ---------------------------------------------------------------------------
__global__ __launch_bounds__(256) void gemm_pre(const float* __restrict__ A,
                                                const float* __restrict__ W,
                                                const float* __restrict__ b1,
                                                float* __restrict__ C) {
  __shared__ float As_[16][64];
  __shared__ float Bs_[16][64];
  const int t = threadIdx.x;
  const int tx = t & 15, ty = t >> 4;
  const int m0 = blockIdx.y * 64;
  const int n0 = blockIdx.x * 64;
  const int ar = t >> 2, ac4 = (t & 3) << 2;
  const int bk = t >> 4, bn4 = (t & 15) << 2;
  float acc[4][4] = {};
  for (int k0 = 0; k0 < K_TOTAL; k0 += 16) {
    float4 av = *reinterpret_cast<const float4*>(A + (size_t)(m0 + ar) * K_TOTAL + k0 + ac4);
    As_[ac4 + 0][ar] = av.x;
    As_[ac4 + 1][ar] = av.y;
    As_[ac4 + 2][ar] = av.z;
    As_[ac4 + 3][ar] = av.w;
    float4 bv = make_float4(0.f, 0.f, 0.f, 0.f);
    const int gn = n0 + bn4;
    if (gn < N_TOTAL)
      bv = *reinterpret_cast<const float4*>(W + (size_t)(k0 + bk) * N_TOTAL + gn);
    *reinterpret_cast<float4*>(&Bs_[bk][bn4]) = bv;
    __syncthreads();
#pragma unroll
    for (int kk = 0; kk < 16; ++kk) {
      float4 a = *reinterpret_cast<const float4*>(&As_[kk][ty << 2]);
      float4 b = *reinterpret_cast<const float4*>(&Bs_[kk][tx << 2]);
      const float aa[4] = {a.x, a.y, a.z, a.w};
      const float bb[4] = {b.x, b.y, b.z, b.w};
#pragma unroll
      for (int i = 0; i < 4; ++i)
#pragma unroll
        for (int j = 0; j < 4; ++j)
          acc[i][j] = fmaf(aa[i], bb[j], acc[i][j]);
    }
    __syncthreads();
  }
#pragma unroll
  for (int j = 0; j < 4; ++j) {
    const int n = n0 + (tx << 2) + j;
    if (n < N_TOTAL) {
      const float bj = b1[n];
#pragma unroll
      for (int i = 0; i < 4; ++i) {
        const int m = m0 + (ty << 2) + i;
        C[(size_t)m * N_TOTAL + n] = acc[i][j] + bj;
      }
    }
  }
}

// ---------------------------------------------------------------------------
// JAX threefry2x32, key(42) -> (0,42); partitionable random_bits (32-bit)
// ---------------------------------------------------------------------------
__device__ __forceinline__ float jax_gumbel(uint32_t idx) {
  const uint32_t ks0 = 0u;
  const uint32_t ks1 = 42u;
  const uint32_t ks2 = 0x1BD11BDAu ^ ks0 ^ ks1;
  uint32_t x0 = ks0;
  uint32_t x1 = idx + ks1;
#define TF_ROUND(r) { x0 += x1; x1 = (x1 << (r)) | (x1 >> (32 - (r))); x1 ^= x0; }
  TF_ROUND(13) TF_ROUND(15) TF_ROUND(26) TF_ROUND(6)
  x0 += ks1; x1 += ks2 + 1u;
  TF_ROUND(17) TF_ROUND(29) TF_ROUND(16) TF_ROUND(24)
  x0 += ks2; x1 += ks0 + 2u;
  TF_ROUND(13) TF_ROUND(15) TF_ROUND(26) TF_ROUND(6)
  x0 += ks0; x1 += ks1 + 3u;
  TF_ROUND(17) TF_ROUND(29) TF_ROUND(16) TF_ROUND(24)
  x0 += ks1; x1 += ks2 + 4u;
  TF_ROUND(13) TF_ROUND(15) TF_ROUND(26) TF_ROUND(6)
  x0 += ks2; x1 += ks0 + 5u;
#undef TF_ROUND
  const uint32_t bits = x0 ^ x1;
  union { uint32_t u; float f; } cvt;
  cvt.u = (bits >> 9) | 0x3F800000u;
  const float fl = cvt.f - 1.0f;
  const float TINY = 1.1754943508222875e-38f;
  const float u = fmaxf(TINY, fl * 1.0f + TINY);
  return -logf(-logf(u));
}

// ---------------------------------------------------------------------------
// head_kernel: per row -- softmax (in-place), gumbel argmax, gather+relu+add
// ---------------------------------------------------------------------------
__global__ __launch_bounds__(256) void head_kernel(
    float* __restrict__ pre_probs,
    const float* __restrict__ core,
    const float* __restrict__ W2,
    const float* __restrict__ b2,
    float* __restrict__ out1) {
  const int row = blockIdx.x;
  const int t = threadIdx.x;
  const int lane = t & 63, wid = t >> 6;

  __shared__ float s_max[4];
  __shared__ float s_sum[4];
  __shared__ float s_av[4];
  __shared__ int   s_ai[4];

  float* xrow = pre_probs + (size_t)row * N_TOTAL;
  const int c0 = t, c1 = t + 256, c2 = t + 512;
  const bool v1 = (c1 < N_TOTAL), v2 = (c2 < N_TOTAL);
  const float NEG_INF = -__builtin_inff();

  const float x0v = xrow[c0];
  const float x1v = v1 ? xrow[c1] : NEG_INF;
  const float x2v = v2 ? xrow[c2] : NEG_INF;

  float vmax = fmaxf(x0v, fmaxf(x1v, x2v));
#pragma unroll
  for (int off = 32; off > 0; off >>= 1)
    vmax = fmaxf(vmax, __shfl_xor(vmax, off, 64));
  if (lane == 0) s_max[wid] = vmax;
  __syncthreads();
  const float m = fmaxf(fmaxf(s_max[0], s_max[1]), fmaxf(s_max[2], s_max[3]));

  const float e0 = expf(x0v - m);
  const float e1 = v1 ? expf(x1v - m) : 0.0f;
  const float e2 = v2 ? expf(x2v - m) : 0.0f;
  float vsum = e0 + e1 + e2;
#pragma unroll
  for (int off = 32; off > 0; off >>= 1)
    vsum += __shfl_xor(vsum, off, 64);
  if (lane == 0) s_sum[wid] = vsum;
  __syncthreads();
  const float sum = (s_sum[0] + s_sum[1]) + (s_sum[2] + s_sum[3]);

  const float lse = logf(sum);
  xrow[c0] = e0 / sum;
  if (v1) xrow[c1] = e1 / sum;
  if (v2) xrow[c2] = e2 / sum;

  const uint32_t base = (uint32_t)row * (uint32_t)N_TOTAL;
  float bv = jax_gumbel(base + c0) + ((x0v - m) - lse);
  int bi = c0;
  if (v1) {
    const float s1 = jax_gumbel(base + c1) + ((x1v - m) - lse);
    if (s1 > bv) { bv = s1; bi = c1; }
  }
  if (v2) {
    const float s2 = jax_gumbel(base + c2) + ((x2v - m) - lse);
    if (s2 > bv) { bv = s2; bi = c2; }
  }
#pragma unroll
  for (int off = 32; off > 0; off >>= 1) {
    const float ov = __shfl_xor(bv, off, 64);
    const int oi = __shfl_xor(bi, off, 64);
    if (ov > bv || (ov == bv && oi < bi)) { bv = ov; bi = oi; }
  }
  if (lane == 0) { s_av[wid] = bv; s_ai[wid] = bi; }
  __syncthreads();
  float best = s_av[0]; int action = s_ai[0];
#pragma unroll
  for (int w = 1; w < 4; ++w) {
    if (s_av[w] > best || (s_av[w] == best && s_ai[w] < action)) {
      best = s_av[w]; action = s_ai[w];
    }
  }

  const float* __restrict__ w2row = W2 + (size_t)action * D_TOTAL;
  const float* __restrict__ crow = core + (size_t)row * D_TOTAL;
  float* __restrict__ orow = out1 + (size_t)row * D_TOTAL;
#pragma unroll
  for (int d = t; d < D_TOTAL; d += 256) {
    const float h = w2row[d] + b2[d];
    orow[d] = fmaxf(h, 0.0f) + crow[d];
  }
}

// ---------------------------------------------------------------------------
extern "C" void kernel_launch(void* const* d_in, const int* in_sizes, int n_in,
                              void* d_out, int out_size, void* d_ws, size_t ws_size,
                              hipStream_t stream) {
  const float* core = (const float*)d_in[0];  // [16384,1024]
  const float* W1   = (const float*)d_in[1];  // [1024,572]
  const float* b1   = (const float*)d_in[2];  // [572]
  const float* W2   = (const float*)d_in[3];  // [572,1024]
  const float* b2   = (const float*)d_in[4];  // [1024]

  float* probs = (float*)d_out;                              // [16384,572]
  float* out1  = (float*)d_out + (size_t)M_TOTAL * N_TOTAL;  // [16384,1024]

  const size_t wneed = (size_t)2 * N_PAD * K_TOTAL * sizeof(f16);  // 2.6 MB
  if (ws_size >= wneed) {
    f16* wHi = (f16*)d_ws;
    f16* wLo = wHi + (size_t)N_PAD * K_TOTAL;
    convert_w<<<dim3(N_PAD / 32, K_TOTAL / 32), 256, 0, stream>>>(W1, wHi, wLo);
    gemm_fused<<<(M_TOTAL / BM) * (N_PAD / BN), 256, 0, stream>>>(core, wHi, wLo, b1, probs);
  } else {
    gemm_pre<<<dim3((N_TOTAL + 63) / 64, M_TOTAL / 64), 256, 0, stream>>>(core, W1, b1, probs);
  }

  head_kernel<<<M_TOTAL, 256, 0, stream>>>(probs, core, W2, b2, out1);
}